// Round 5
// baseline (519.909 us; speedup 1.0000x reference)
//
#include <hip/hip_runtime.h>

// Unfold (im2col): IN (4,64,224,224) f32, K=3x3, pad=1, stride=1, dil=1
// (reference nh=k+dil quirk -> output spatial 223x223)
// out[ch][pos], ch=(b*64+c)*9+i*3+j (2304 channels), pos=oh*223+ow (49729)
//   = x[b,c,oh+i-1,ow+j-1] (zero-padded)
//
// V5 = V4 body + XCD-aware block swizzle.
// V1/V2/V4 (wildly different instr mixes) all ~226-259us => traffic-bound.
// Hidden traffic: each 196KB input plane is read by 117 blocks that default
// dispatch spreads over all 8 XCDs (private L2s) => up to 8x read
// amplification (~411MB extra). Remap a 1D grid so XCD k (= flat%8) owns
// planes [32k,32k+32): each plane is fetched into exactly one L2, once.
// NT stores (evict-first) keep L2 free for the plane data.

#define OW       223u
#define OSP      49729u      // 223*223
#define IW       224u
#define PLANE_IN 50176u      // 224*224
#define PER_XCD  3744u       // 29952 blocks / 8 XCDs
#define BPP      117u        // blocks per plane = 9 ch * 13 x-chunks

typedef float vf4 __attribute__((ext_vector_type(4)));
typedef vf4 vf4u __attribute__((aligned(4)));   // 4B-aligned vector view

__global__ __launch_bounds__(256) void unfold223_v5(
    const float* __restrict__ x, float* __restrict__ out)
{
    // --- XCD-aware swizzle (bijective: 29952 = 8 * 3744 exactly) ---
    const unsigned flat = blockIdx.x;
    const unsigned work = (flat & 7u) * PER_XCD + (flat >> 3);
    const unsigned q    = work / BPP;           // input plane b*64+c (0..255)
    const unsigned t    = work - q * BPP;
    const unsigned ch9  = t / 13u;              // i*3+j (0..8)
    const unsigned bx   = t - ch9 * 13u;        // x-chunk (0..12)
    const unsigned ch   = q * 9u + ch9;         // output channel (uniform)

    const int im1 = (int)(ch9 / 3u) - 1;        // i-1 (uniform)
    const int jm1 = (int)(ch9 % 3u) - 1;        // j-1 (uniform)
    const int off = im1 * (int)IW + jm1;        // uniform src offset
    const float* __restrict__ xq = x + q * PLANE_IN;
    float* __restrict__ och = out + (unsigned long long)ch * OSP;

    // OSP % 4 == 1 -> channel base alignment rotates; a = first 16B-aligned elem
    const unsigned a  = (4u - (ch & 3u)) & 3u;
    const unsigned nv = (OSP - a) >> 2;         // aligned quad count
    const unsigned tid = threadIdx.x;

    // head [0,a) + tail: <=5 scalar elems per channel (x-chunk 0 only)
    if (bx == 0u && tid < 8u) {
        const unsigned nhead = a;
        const unsigned ntail = OSP - a - 4u * nv;
        if (tid < nhead + ntail) {
            unsigned pos = (tid < nhead) ? tid : (a + 4u * nv + (tid - nhead));
            unsigned oh = pos / OW;
            unsigned ow = pos - oh * OW;
            int ih = (int)oh + im1;
            int iw = (int)ow + jm1;
            bool valid = ((unsigned)ih < 224u) && ((unsigned)iw < 224u);
            unsigned idx = valid ? ((unsigned)ih * IW + (unsigned)iw) : 0u;
            float val = xq[idx];
            och[pos] = valid ? val : 0.0f;
        }
    }

    // main: 4 quads per thread, chunk-strided
    const unsigned vbase = bx * 1024u + tid;
#pragma unroll
    for (int k = 0; k < 4; ++k) {
        const unsigned v = vbase + (unsigned)(k * 256);
        if (v < nv) {
            const unsigned pos = a + 4u * v;
            const unsigned oh0 = pos / OW;          // one magic-mul divide
            const unsigned ow0 = pos - oh0 * OW;
            // src flat index of elem0: (oh0+im1)*224 + ow0+jm1 = pos + oh0 + off
            const int src = (int)pos + (int)oh0 + (int)off;
            // fast iff no row-cross and no pad touch:
            const bool fast = (ow0 <= 219u)
                           && ((int)ow0 + jm1 >= 0)
                           && ((int)oh0 + im1 >= 0);
            vf4 res;
            if (fast) {
                res = *reinterpret_cast<const vf4u*>(xq + src);
            } else {
                float vals[4];
#pragma unroll
                for (int e = 0; e < 4; ++e) {
                    unsigned ow = ow0 + (unsigned)e;
                    unsigned oh = oh0;
                    if (ow >= OW) { ow -= OW; oh += 1u; }
                    int ih = (int)oh + im1;
                    int iw = (int)ow + jm1;
                    bool valid = ((unsigned)ih < 224u) && ((unsigned)iw < 224u);
                    unsigned idx = valid ? ((unsigned)ih * IW + (unsigned)iw) : 0u;
                    float val = xq[idx];
                    vals[e] = valid ? val : 0.0f;
                }
                res[0] = vals[0]; res[1] = vals[1];
                res[2] = vals[2]; res[3] = vals[3];
            }
            __builtin_nontemporal_store(res, reinterpret_cast<vf4*>(och + pos));
        }
    }
}

extern "C" void kernel_launch(void* const* d_in, const int* in_sizes, int n_in,
                              void* d_out, int out_size, void* d_ws, size_t ws_size,
                              hipStream_t stream)
{
    const float* x = (const float*)d_in[0];
    float* out = (float*)d_out;
    // 256 planes * 9 channels * 13 x-chunks = 29952 blocks (1D, swizzled in-kernel)
    unfold223_v5<<<dim3(29952), dim3(256), 0, stream>>>(x, out);
}